// Round 18
// baseline (160.183 us; speedup 1.0000x reference)
//
#include <hip/hip_runtime.h>
#include <hip/hip_bf16.h>
#include <stdint.h>

#define DM   1024
#define LSEQ 2048
#define NB   4

typedef __attribute__((ext_vector_type(8))) short  short8;
typedef __attribute__((ext_vector_type(4))) float  floatx4;

__device__ __forceinline__ ushort f2b(float x) {
    union { float f; uint32_t u; } v; v.f = x;
    uint32_t b = v.u + 0x7FFF + ((v.u >> 16) & 1);   // RNE
    return (ushort)(b >> 16);
}
__device__ __forceinline__ float b2f(ushort x) {
    union { uint32_t u; float f; } v; v.u = ((uint32_t)x) << 16;
    return v.f;
}

// ---------------------------------------------------------------- fused cvt (u + all weights)
__global__ __launch_bounds__(256) void cvt_all_kernel(const float* __restrict__ u,
                                                      const float* __restrict__ Wq,
                                                      const float* __restrict__ Wk,
                                                      const float* __restrict__ Wv,
                                                      const float* __restrict__ Wo,
                                                      ushort* __restrict__ U16,
                                                      ushort* __restrict__ Wcat) {
    const int nu  = NB * LSEQ * DM / 8;
    const int per = DM * DM / 8;
    int i = blockIdx.x * 256 + threadIdx.x;
    const float* src; ushort* dst; int j;
    if (i < nu) { src = u; dst = U16; j = i; }
    else {
        int k = i - nu;
        int r = k / per;                              // uniform per block
        src = (r == 0) ? Wq : (r == 1) ? Wk : (r == 2) ? Wv : Wo;
        dst = Wcat + (size_t)r * (DM * DM);
        j = k - r * per;
    }
    const float4* p = (const float4*)src + (size_t)j * 2;
    float4 a = p[0], b = p[1];
    union { ushort us[8]; uint4 v; } o;
    o.us[0] = f2b(a.x); o.us[1] = f2b(a.y); o.us[2] = f2b(a.z); o.us[3] = f2b(a.w);
    o.us[4] = f2b(b.x); o.us[5] = f2b(b.y); o.us[6] = f2b(b.z); o.us[7] = f2b(b.w);
    *(uint4*)(dst + (size_t)j * 8) = o.v;
}

// ---------------------------------------------------------------- gemm_v4: high-occupancy BK=32 GEMM
// C[m][n] = sum_k A[m][k]*B[n][k] + bias[n].  K=1024, BK=32, BM=128, BN template (256|128).
// 512 thr = 8 waves (2M x 4N), wave tile 64 x BN/4.  LDS = 16KB(A) + 2*BN*64(B):
//   BN=256 -> 48KB -> 3 blocks/CU (QKV, grid 768 = 3x256 exact)
//   BN=128 -> 32KB -> 2+ blocks/CU co-resident (out-proj, grid 512)
// Cross-block overlap hides barrier/vmcnt drains (m103/m114 mechanism).
// Counted vmcnt(1 + BN/128): gloads/wave/tile, 2 tiles in flight.
// MODE 0: n=proj*1024+d, bf16 x4 store along l into C0/C1/C2 (b,d,l). MODE 1: f32 row-major C0.
template <int MODE, int BN>
__global__ __launch_bounds__(512, 2) void gemm_v4(const ushort* __restrict__ Aw,
                                                  const ushort* __restrict__ Bw,
                                                  const float* __restrict__ b0,
                                                  const float* __restrict__ b1,
                                                  const float* __restrict__ b2,
                                                  void* __restrict__ C0v,
                                                  void* __restrict__ C1v,
                                                  void* __restrict__ C2v,
                                                  int N, int nbx) {
    constexpr int K = 1024, BK = 32, NT = K / BK;
    constexpr int NJ    = BN / 64;       // j-frags per wave (4 | 2)
    constexpr int NBG   = BN / 128;      // B gloads per wave per tile (2 | 1)
    constexpr int VMS   = 1 + NBG;       // steady vmcnt
    constexpr int ASLOT = 128 * 64;      // 8 KB
    constexpr int BSLOT = BN * 64;       // 16 | 8 KB
    constexpr int BOFF  = 2 * ASLOT;
    __shared__ char lds[BOFF + 2 * BSLOT];   // 48 | 32 KB

    const int tid   = threadIdx.x;
    const int wave  = tid >> 6;
    const int lane  = tid & 63;
    const int qlane = lane & 15;
    const int qk    = lane >> 4;
    const int z3    = qlane & 3;         // row&3 for frag reads (row stride 64B = 4 chunks)
    const int wm    = wave >> 2;         // 0..1
    const int wn    = wave & 3;          // 0..3

    int flat = blockIdx.y * nbx + blockIdx.x;
    int nwg  = nbx * gridDim.y;
    int swz  = (flat & 7) * (nwg >> 3) + (flat >> 3);
    const int tn = (swz % nbx) * BN;
    const int tm = (swz / nbx) * 128;

    // rows are 32 bf16 = 64B = 4 chunks of 16B; pre-swizzle source so phys chunk = c ^ (row&3)
    const int srcChunkOff = (((lane & 3) ^ ((lane >> 2) & 3)) * 8);
    const int srcRow      = lane >> 2;   // 0..15

#define STAGE4(TT)                                                                           \
    {                                                                                        \
        const int k0_ = (TT) * BK;                                                           \
        {                                                                                    \
            const int trow = tm + wave * 16 + srcRow;                                        \
            const ushort* src = Aw + (size_t)trow * K + k0_ + srcChunkOff;                   \
            __builtin_amdgcn_global_load_lds(                                                \
                (const __attribute__((address_space(1))) void*)src,                          \
                (__attribute__((address_space(3))) void*)(lds + ((TT) & 1) * ASLOT +         \
                                                          wave * 1024), 16, 0, 0);           \
        }                                                                                    \
        _Pragma("unroll")                                                                    \
        for (int jj = 0; jj < NBG; ++jj) {                                                   \
            const int trow = tn + wave * (16 * NBG) + jj * 16 + srcRow;                      \
            const ushort* src = Bw + (size_t)trow * K + k0_ + srcChunkOff;                   \
            __builtin_amdgcn_global_load_lds(                                                \
                (const __attribute__((address_space(1))) void*)src,                          \
                (__attribute__((address_space(3))) void*)(lds + BOFF + ((TT) & 1) * BSLOT +  \
                                                          wave * (1024 * NBG) + jj * 1024), 16, 0, 0); \
        }                                                                                    \
    }

    short8 afA[4], afB[4], bfA[NJ], bfB[NJ];
    floatx4 acc[4][NJ] = {};

#define LD4A(TT, AF)                                                                         \
    {                                                                                        \
        const char* Ab = lds + ((TT) & 1) * ASLOT;                                           \
        _Pragma("unroll")                                                                    \
        for (int i = 0; i < 4; ++i)                                                          \
            AF[i] = *(const short8*)(Ab + (wm * 64 + i * 16 + qlane) * 64 +                  \
                                     ((qk ^ z3) << 4));                                      \
    }
#define LD4B(TT, BF)                                                                         \
    {                                                                                        \
        const char* Bb = lds + BOFF + ((TT) & 1) * BSLOT;                                    \
        _Pragma("unroll")                                                                    \
        for (int j = 0; j < NJ; ++j)                                                         \
            BF[j] = *(const short8*)(Bb + (wn * (16 * NJ) + j * 16 + qlane) * 64 +           \
                                     ((qk ^ z3) << 4));                                      \
    }
#define MFMAQ4(H, AF, BF)                                                                    \
    __builtin_amdgcn_s_setprio(1);                                                          \
    _Pragma("unroll")                                                                        \
    for (int i = 0; i < 4; ++i)                                                              \
        _Pragma("unroll")                                                                    \
        for (int j = (NJ / 2) * (H); j < (NJ / 2) * (H) + (NJ / 2); ++j)                     \
            acc[i][j] = __builtin_amdgcn_mfma_f32_16x16x32_bf16(AF[i], BF[j], acc[i][j], 0, 0, 0); \
    __builtin_amdgcn_s_setprio(0);
#define BARX  __builtin_amdgcn_s_barrier(); __builtin_amdgcn_sched_barrier(0)
#define VM_S  asm volatile("s_waitcnt vmcnt(%0)" :: "i"(VMS) : "memory")

    // prologue: stage tiles 0,1; confirm tile 0; load its frags; fence reads.
    STAGE4(0); STAGE4(1);
    VM_S;
    BARX;
    LD4A(0, afA); LD4B(0, bfA);
    asm volatile("s_waitcnt lgkmcnt(0)" ::: "memory");
    __builtin_amdgcn_sched_barrier(0);
    BARX;

#define TILE4(T, AFc, BFc, AFn, BFn)                                                         \
    {                                                                                        \
        MFMAQ4(0, AFc, BFc);                                                                 \
        BARX;                                                                                \
        if ((T) + 2 < NT) STAGE4((T) + 2);                                                   \
        MFMAQ4(1, AFc, BFc);                                                                 \
        if ((T) + 2 < NT)      { VM_S; }                                                     \
        else if ((T) + 1 < NT) { asm volatile("s_waitcnt vmcnt(0)" ::: "memory"); }          \
        BARX;                                                                                \
        if ((T) + 1 < NT) { LD4A((T) + 1, AFn); LD4B((T) + 1, BFn); }                        \
    }

    for (int t = 0; t < NT; t += 2) {
        TILE4(t,     afA, bfA, afB, bfB);
        TILE4(t + 1, afB, bfB, afA, bfA);
    }
#undef TILE4
#undef STAGE4
#undef LD4A
#undef LD4B
#undef MFMAQ4
#undef BARX
#undef VM_S

#pragma unroll
    for (int i = 0; i < 4; ++i)
#pragma unroll
    for (int j = 0; j < NJ; ++j) {
        int n  = tn + wn * (16 * NJ) + j * 16 + qlane;   // C/D col = lane&15
        int m0 = tm + wm * 64 + i * 16 + qk * 4;         // C/D row = (lane>>4)*4 + r
        if (MODE == 0) {
            int proj = n >> 10, dd = n & (DM - 1);
            const float* bb = (proj == 0) ? b0 : (proj == 1) ? b1 : b2;
            ushort* Cb      = (ushort*)((proj == 0) ? C0v : (proj == 1) ? C1v : C2v);
            float bv = bb[dd];
            int b = m0 >> 11, l = m0 & (LSEQ - 1);
            ushort4 val;
            val.x = f2b(acc[i][j][0] + bv);
            val.y = f2b(acc[i][j][1] + bv);
            val.z = f2b(acc[i][j][2] + bv);
            val.w = f2b(acc[i][j][3] + bv);
            *(ushort4*)(Cb + ((size_t)b * DM + dd) * LSEQ + l) = val;
        } else {
            float* C0 = (float*)C0v;
            float bv = b0[n];
#pragma unroll
            for (int r = 0; r < 4; ++r)
                C0[(size_t)(m0 + r) * N + n] = acc[i][j][r] + bv;
        }
    }
}

// ---------------------------------------------------------------- FUSED double MFMA Toeplitz causal conv
// (round-16/17 verbatim — A-build with address-folded parity, 5 dword reads + alignbit)
#define KSTR 2096
#define XSTR 2248

__global__ __launch_bounds__(256, 4) void conv_fused_kernel(const ushort* __restrict__ x,
                                                            const float* __restrict__ ker1,
                                                            const float* __restrict__ scale1,
                                                            const ushort* __restrict__ gate1,
                                                            const float* __restrict__ ker2,
                                                            const float* __restrict__ scale2,
                                                            const ushort* __restrict__ gate2,
                                                            ushort* __restrict__ out) {
    __shared__ ushort krev1[KSTR];
    __shared__ ushort krev2[KSTR];
    __shared__ ushort xs[4 * XSTR];
    const int d    = blockIdx.x;
    const int tid  = threadIdx.x;
    const int wave = tid >> 6;          // 0..3
    const int lane = tid & 63;

    {
        const ushort* src = x + ((size_t)wave * DM + d) * LSEQ + lane * 8;
        char* dst = (char*)xs + wave * (XSTR * 2) + 256;
#pragma unroll
        for (int c = 0; c < 4; ++c)
            __builtin_amdgcn_global_load_lds((const __attribute__((address_space(1))) void*)(src + c * 512),
                                             (__attribute__((address_space(3))) void*)(dst + c * 1024),
                                             16, 0, 0);
    }
    {
        int e0 = tid * 8;
        const float* k1p = ker1 + (size_t)d * LSEQ + e0;
        const float* k2p = ker2 + (size_t)d * LSEQ + e0;
        float4 a1 = *(const float4*)(k1p),     b1 = *(const float4*)(k1p + 4);
        float4 a2 = *(const float4*)(k2p),     b2 = *(const float4*)(k2p + 4);
        ushort4 o;                                    // krev[2060-e + j] = ker[e+3-j]
        o.x = f2b(a1.w); o.y = f2b(a1.z); o.z = f2b(a1.y); o.w = f2b(a1.x);
        *(ushort4*)(krev1 + (2060 - e0)) = o;
        o.x = f2b(b1.w); o.y = f2b(b1.z); o.z = f2b(b1.y); o.w = f2b(b1.x);
        *(ushort4*)(krev1 + (2056 - e0)) = o;
        o.x = f2b(a2.w); o.y = f2b(a2.z); o.z = f2b(a2.y); o.w = f2b(a2.x);
        *(ushort4*)(krev2 + (2060 - e0)) = o;
        o.x = f2b(b2.w); o.y = f2b(b2.z); o.z = f2b(b2.y); o.w = f2b(b2.x);
        *(ushort4*)(krev2 + (2056 - e0)) = o;
        uint4 z = {0, 0, 0, 0};
        if (tid < 2) {
            *(uint4*)((char*)krev1 + tid * 16) = z;
            *(uint4*)((char*)krev2 + tid * 16) = z;
        }
        if (tid >= 2 && tid < 6) {
            *(uint4*)((char*)krev1 + 4128 + (tid - 2) * 16) = z;
            *(uint4*)((char*)krev2 + 4128 + (tid - 2) * 16) = z;
        }
        if (tid >= 64 && tid < 128) {
            int b = (tid - 64) >> 4, c = (tid - 64) & 15;
            *(uint4*)((char*)xs + b * (XSTR * 2) + c * 16) = z;
        }
        if (tid >= 128 && tid < 144) {
            int b = (tid - 128) >> 2, c = (tid - 128) & 3;
            *(uint4*)((char*)xs + b * (XSTR * 2) + 4352 + c * 16) = z;
        }
    }
    __syncthreads();

    const int qn = lane & 15;
    const int qk = lane >> 4;

    int g[4] = {wave, 7 - wave, 8 + wave, 15 - wave};
    const int smax_all = 128 * (15 - wave) + 128;

    const int lbase = (qn & 3) * XSTR + 128 + 16 * (qn >> 2) + 8 * qk;

#define CSTEP(KR, ACC, SS, FP)                                                               \
    {                                                                                        \
        int b_el = 2063 - qn + 8 * qk - (SS);                                                \
        int A0 = b_el & ~1;                                                                  \
        uint sh = (uint)(b_el & 1) * 16u;                                                    \
        uint e0 = *(const uint*)((KR) + A0);                                                 \
        uint e1 = *(const uint*)((KR) + A0 + 2);                                             \
        uint e2 = *(const uint*)((KR) + A0 + 4);                                             \
        uint e3 = *(const uint*)((KR) + A0 + 6);                                             \
        uint e4 = *(const uint*)((KR) + A0 + 8);                                             \
        union { uint u[4]; short8 v; } Af;                                                   \
        Af.u[0] = __builtin_amdgcn_alignbit(e1, e0, sh);                                     \
        Af.u[1] = __builtin_amdgcn_alignbit(e2, e1, sh);                                     \
        Af.u[2] = __builtin_amdgcn_alignbit(e3, e2, sh);                                     \
        Af.u[3] = __builtin_amdgcn_alignbit(e4, e3, sh);                                     \
        _Pragma("unroll")                                                                    \
        for (int gi = 0; gi < 4; ++gi) {                                                     \
            if ((SS) <= 128 * g[gi] + 128) {                                                 \
                short8 fN = *(const short8*)(xs + lbase + 128 * g[gi] - (SS));               \
                ACC[gi][0] = __builtin_amdgcn_mfma_f32_16x16x32_bf16(Af.v, fN, ACC[gi][0], 0, 0, 0); \
                ACC[gi][1] = __builtin_amdgcn_mfma_f32_16x16x32_bf16(Af.v, FP[gi], ACC[gi][1], 0, 0, 0); \
                FP[gi] = fN;                                                                 \
            }                                                                                \
        }                                                                                    \
    }

    // ================= pass 1: k -> kv (in LDS) =================
    {
        floatx4 acc[4][2] = {};
        short8 fE[4], fO[4];
#pragma unroll
        for (int gi = 0; gi < 4; ++gi) {
            fE[gi] = *(const short8*)(xs + lbase + 128 * g[gi] + 64);
            fO[gi] = *(const short8*)(xs + lbase + 128 * g[gi] + 32);
        }
        for (int s = 0; s <= smax_all; s += 64) {
            CSTEP(krev1, acc, s, fE);
            if (s + 32 <= smax_all) CSTEP(krev1, acc, s + 32, fO);
        }

        __syncthreads();                       // all pass-1 LDS reads done before overwrite
        const float sc = scale1[d];
#pragma unroll
        for (int gi = 0; gi < 4; ++gi) {
#pragma unroll
            for (int m = 0; m < 2; ++m) {
                int p  = 8 * g[gi] + 4 * m + (qn >> 2);
                int b  = qn & 3;
                int l0 = 16 * p + 4 * qk;
                size_t off = ((size_t)b * DM + d) * LSEQ + l0;
                ushort4 xv = *(const ushort4*)(xs + b * XSTR + 128 + l0);   // own slots only
                ushort4 gv = *(const ushort4*)(gate1 + off);
                ushort4 ov;
                ov.x = f2b((acc[gi][m][0] + sc * b2f(xv.x)) * b2f(gv.x));
                ov.y = f2b((acc[gi][m][1] + sc * b2f(xv.y)) * b2f(gv.y));
                ov.z = f2b((acc[gi][m][2] + sc * b2f(xv.z)) * b2f(gv.z));
                ov.w = f2b((acc[gi][m][3] + sc * b2f(xv.w)) * b2f(gv.w));
                *(ushort4*)(xs + b * XSTR + 128 + l0) = ov;                 // kv into LDS
            }
        }
        __syncthreads();                       // kv complete before pass-2 reads
    }

    // ================= pass 2: kv -> yq (to global) =================
    {
        floatx4 acc[4][2] = {};
        short8 fE[4], fO[4];
#pragma unroll
        for (int gi = 0; gi < 4; ++gi) {
            fE[gi] = *(const short8*)(xs + lbase + 128 * g[gi] + 64);
            fO[gi] = *(const short8*)(xs + lbase + 128 * g[gi] + 32);
        }
        for (int s = 0; s <= smax_all; s += 64) {
            CSTEP(krev2, acc, s, fE);
            if (s + 32 <= smax_all) CSTEP(krev2, acc, s + 32, fO);
        }

        const float sc = scale2[d];
#pragma unroll
        for (int gi = 0; gi < 4; ++gi) {
#pragma unroll
            for (int m = 0; m < 2; ++m) {
                int p  = 8 * g[gi] + 4 * m + (qn >> 2);
                int b  = qn & 3;
                int l0 = 16 * p + 4 * qk;
                size_t off = ((size_t)b * DM + d) * LSEQ + l0;
                ushort4 xv = *(const ushort4*)(xs + b * XSTR + 128 + l0);
                ushort4 gv = *(const ushort4*)(gate2 + off);
                ushort4 ov;
                ov.x = f2b((acc[gi][m][0] + sc * b2f(xv.x)) * b2f(gv.x));
                ov.y = f2b((acc[gi][m][1] + sc * b2f(xv.y)) * b2f(gv.y));
                ov.z = f2b((acc[gi][m][2] + sc * b2f(xv.z)) * b2f(gv.z));
                ov.w = f2b((acc[gi][m][3] + sc * b2f(xv.w)) * b2f(gv.w));
                *(ushort4*)(out + off) = ov;
            }
        }
    }
#undef CSTEP
}

// ---------------------------------------------------------------- (B,DM,L) bf16 -> (B*L,DM) bf16
__global__ __launch_bounds__(256) void transpose_bf16(const ushort* __restrict__ in,
                                                      ushort* __restrict__ out) {
    __shared__ ushort t[32][36];
    const int l0 = blockIdx.x * 32;
    const int d0 = blockIdx.y * 32;
    const int b  = blockIdx.z;
    const int q  = threadIdx.x & 7;
    const int r  = threadIdx.x >> 3;
    *(ushort4*)(&t[r][q * 4]) = *(const ushort4*)(in + ((size_t)b * DM + d0 + r) * LSEQ + l0 + q * 4);
    __syncthreads();
    ushort4 o;
    o.x = t[q * 4 + 0][r]; o.y = t[q * 4 + 1][r]; o.z = t[q * 4 + 2][r]; o.w = t[q * 4 + 3][r];
    *(ushort4*)(out + ((size_t)b * LSEQ + l0 + r) * DM + d0 + q * 4) = o;
}

// ---------------------------------------------------------------- launch
extern "C" void kernel_launch(void* const* d_in, const int* in_sizes, int n_in,
                              void* d_out, int out_size, void* d_ws, size_t ws_size,
                              hipStream_t stream) {
    const float* u        = (const float*)d_in[0];
    const float* Wq       = (const float*)d_in[1];
    const float* bq       = (const float*)d_in[2];
    const float* Wk       = (const float*)d_in[3];
    const float* bk       = (const float*)d_in[4];
    const float* Wv       = (const float*)d_in[5];
    const float* bv       = (const float*)d_in[6];
    const float* k_kernel = (const float*)d_in[7];
    const float* k_D      = (const float*)d_in[8];
    const float* ssm_ker  = (const float*)d_in[9];
    const float* Dv       = (const float*)d_in[10];
    const float* Wo       = (const float*)d_in[11];
    const float* bo       = (const float*)d_in[12];
    float* outp = (float*)d_out;

    char* ws = (char*)d_ws;
    ushort* Q    = (ushort*)(ws);                    // 16 MB (bf16 b,d,l)
    ushort* KV   = (ushort*)(ws + (16ull << 20));    // 16 MB (k -> yq, in place)
    ushort* V    = (ushort*)(ws + (32ull << 20));    // 16 MB
    ushort* U16  = (ushort*)(ws + (48ull << 20));    // 16 MB (u bf16)
    ushort* YT   = (ushort*)(ws + (64ull << 20));    // 16 MB (yq transposed)
    ushort* Wcat = (ushort*)(ws + (80ull << 20));    // 8 MB  (Wq|Wk|Wv|Wo bf16)

    const int nu = NB * LSEQ * DM / 8, nw = 4 * DM * DM / 8;
    cvt_all_kernel<<<(nu + nw) / 256, 256, 0, stream>>>(u, Wq, Wk, Wv, Wo, U16, Wcat);

    // fused q/k/v projection: M=8192, N=3072, K=1024; 128x256 tiles, BK=32, 48KB LDS
    // -> grid 12x64 = 768 blocks = exactly one round at 3 blocks/CU.
    dim3 g1(3 * DM / 256, NB * LSEQ / 128);
    gemm_v4<0, 256><<<g1, 512, 0, stream>>>(U16, Wcat, bq, bk, bv, Q, KV, V,
                                            3 * DM, 3 * DM / 256);

    // fused double conv: kv = (k_kernel (*) k + k_D*k) * v ; yq = (ssm_kernel (*) kv + D*kv) * q
    conv_fused_kernel<<<DM, 256, 0, stream>>>(KV, k_kernel, k_D, V, ssm_ker, Dv, Q, KV);

    // (B,DM,L) bf16 -> (B*L,DM) bf16
    dim3 g2(LSEQ / 32, DM / 32, NB);
    transpose_bf16<<<g2, 256, 0, stream>>>(KV, YT);

    // out = YT @ Wo^T + bo : M=8192, N=1024, K=1024; 128x128 tiles, 32KB LDS
    // -> grid 8x64 = 512 blocks, all co-resident at 2 blocks/CU.
    dim3 g3(DM / 128, NB * LSEQ / 128);
    gemm_v4<1, 128><<<g3, 512, 0, stream>>>(YT, Wcat + 3 * DM * DM, bo, bo, bo,
                                            outp, outp, outp, DM, DM / 128);
}

// Round 19
// 156.292 us; speedup vs baseline: 1.0249x; 1.0249x over previous
//
#include <hip/hip_runtime.h>
#include <hip/hip_bf16.h>
#include <stdint.h>

#define DM   1024
#define LSEQ 2048
#define NB   4

typedef __attribute__((ext_vector_type(8))) short  short8;
typedef __attribute__((ext_vector_type(4))) float  floatx4;

__device__ __forceinline__ ushort f2b(float x) {
    union { float f; uint32_t u; } v; v.f = x;
    uint32_t b = v.u + 0x7FFF + ((v.u >> 16) & 1);   // RNE
    return (ushort)(b >> 16);
}
__device__ __forceinline__ float b2f(ushort x) {
    union { uint32_t u; float f; } v; v.u = ((uint32_t)x) << 16;
    return v.f;
}

// ---------------------------------------------------------------- fused cvt (u + all weights)
__global__ __launch_bounds__(256) void cvt_all_kernel(const float* __restrict__ u,
                                                      const float* __restrict__ Wq,
                                                      const float* __restrict__ Wk,
                                                      const float* __restrict__ Wv,
                                                      const float* __restrict__ Wo,
                                                      ushort* __restrict__ U16,
                                                      ushort* __restrict__ Wcat) {
    const int nu  = NB * LSEQ * DM / 8;
    const int per = DM * DM / 8;
    int i = blockIdx.x * 256 + threadIdx.x;
    const float* src; ushort* dst; int j;
    if (i < nu) { src = u; dst = U16; j = i; }
    else {
        int k = i - nu;
        int r = k / per;                              // uniform per block
        src = (r == 0) ? Wq : (r == 1) ? Wk : (r == 2) ? Wv : Wo;
        dst = Wcat + (size_t)r * (DM * DM);
        j = k - r * per;
    }
    const float4* p = (const float4*)src + (size_t)j * 2;
    float4 a = p[0], b = p[1];
    union { ushort us[8]; uint4 v; } o;
    o.us[0] = f2b(a.x); o.us[1] = f2b(a.y); o.us[2] = f2b(a.z); o.us[3] = f2b(a.w);
    o.us[4] = f2b(b.x); o.us[5] = f2b(b.y); o.us[6] = f2b(b.z); o.us[7] = f2b(b.w);
    *(uint4*)(dst + (size_t)j * 8) = o.v;
}

// ---------------------------------------------------------------- unified 2-phase pipelined bf16 GEMM
// (measured-best config: this structure for BOTH QKV (BN=384) and out-proj (BN=256).
// v4 high-occupancy variants improved the QKV dispatch in isolation but regressed the
// whole-pipeline total via co-compilation effects — reverted per measurement.)
template <int MODE, int BN>
__global__ __launch_bounds__(512, 2) void gemm_v2(const ushort* __restrict__ Aw,
                                                  const ushort* __restrict__ Bw,
                                                  const float* __restrict__ b0,
                                                  const float* __restrict__ b1,
                                                  const float* __restrict__ b2,
                                                  void* __restrict__ C0v,
                                                  void* __restrict__ C1v,
                                                  void* __restrict__ C2v,
                                                  int N, int nbx) {
    constexpr int K = 1024, BK = 64, NT = K / BK;
    constexpr int BM     = 128;
    constexpr int NJH    = BN / 128;
    constexpr int ASLOT  = BM * 128;
    constexpr int BSLOT  = BN * 128;
    constexpr int BOFF   = 2 * ASLOT;
    __shared__ char lds[BOFF + 2 * BSLOT];

    const int tid   = threadIdx.x;
    const int wave  = tid >> 6;
    const int lane  = tid & 63;
    const int qlane = lane & 15;
    const int qk    = lane >> 4;
    const int z7    = qlane & 7;
    const int wm    = wave >> 2;
    const int wn    = wave & 3;

    int flat = blockIdx.y * nbx + blockIdx.x;
    int nwg  = nbx * gridDim.y;
    int swz  = (flat & 7) * (nwg >> 3) + (flat >> 3);
    const int tn = (swz % nbx) * BN;
    const int tm = (swz / nbx) * BM;

    const int srcChunkOff = ((lane & 7) ^ (lane >> 3)) * 8;
    const int srcRow      = lane >> 3;

#define STAGE_A(TT)                                                                           \
    {                                                                                         \
        const int trow = tm + wave * 16 + srcRow;                                             \
        char* dst = lds + ((TT) & 1) * ASLOT + wave * 2048;                                   \
        const int k0_ = (TT) * BK;                                                            \
        _Pragma("unroll")                                                                     \
        for (int j = 0; j < 2; ++j) {                                                         \
            const ushort* src = Aw + (size_t)(trow + j * 8) * K + k0_ + srcChunkOff;          \
            __builtin_amdgcn_global_load_lds(                                                 \
                (const __attribute__((address_space(1))) void*)src,                           \
                (__attribute__((address_space(3))) void*)(dst + j * 1024), 16, 0, 0);         \
        }                                                                                     \
    }
#define STAGE_B(TT, H)                                                                        \
    {                                                                                         \
        const int rbase = (H) * (BN / 2) + wave * (8 * NJH);                                  \
        const int trow  = tn + rbase + srcRow;                                                \
        char* dst = lds + BOFF + ((TT) & 1) * BSLOT + rbase * 128;                            \
        const int k0_ = (TT) * BK;                                                            \
        _Pragma("unroll")                                                                     \
        for (int j = 0; j < NJH; ++j) {                                                       \
            const ushort* src = Bw + (size_t)(trow + j * 8) * K + k0_ + srcChunkOff;          \
            __builtin_amdgcn_global_load_lds(                                                 \
                (const __attribute__((address_space(1))) void*)src,                           \
                (__attribute__((address_space(3))) void*)(dst + j * 1024), 16, 0, 0);         \
        }                                                                                     \
    }

    short8 afA[4][2], afB[4][2], bf0[NJH][2], bf1[NJH][2];
    floatx4 acc[2][4][NJH] = {};

#define LDA(TT, AF)                                                                           \
    {                                                                                         \
        const char* Ab = lds + ((TT) & 1) * ASLOT;                                            \
        _Pragma("unroll")                                                                     \
        for (int i = 0; i < 4; ++i) {                                                         \
            int lr = wm * 64 + i * 16 + qlane;                                                \
            _Pragma("unroll")                                                                 \
            for (int ks = 0; ks < 2; ++ks)                                                    \
                AF[i][ks] = *(const short8*)(Ab + lr * 128 + (((ks * 4 + qk) ^ z7) << 4));    \
        }                                                                                     \
    }
#define LDB(TT, NH, BF)                                                                       \
    {                                                                                         \
        const char* Bb = lds + BOFF + ((TT) & 1) * BSLOT;                                     \
        _Pragma("unroll")                                                                     \
        for (int j = 0; j < NJH; ++j) {                                                       \
            int lr = wn * (BN / 4) + (NH) * (NJH * 16) + j * 16 + qlane;                      \
            _Pragma("unroll")                                                                 \
            for (int ks = 0; ks < 2; ++ks)                                                    \
                BF[j][ks] = *(const short8*)(Bb + lr * 128 + (((ks * 4 + qk) ^ z7) << 4));    \
        }                                                                                     \
    }
#define MFMAQ(NH, AF, BF)                                                                     \
    __builtin_amdgcn_s_setprio(1);                                                           \
    _Pragma("unroll")                                                                         \
    for (int ks = 0; ks < 2; ++ks)                                                            \
        _Pragma("unroll")                                                                     \
        for (int i = 0; i < 4; ++i)                                                           \
            _Pragma("unroll")                                                                 \
            for (int j = 0; j < NJH; ++j)                                                     \
                acc[NH][i][j] = __builtin_amdgcn_mfma_f32_16x16x32_bf16(                      \
                    AF[i][ks], BF[j][ks], acc[NH][i][j], 0, 0, 0);                            \
    __builtin_amdgcn_s_setprio(0);
#define BARX  __builtin_amdgcn_s_barrier(); __builtin_amdgcn_sched_barrier(0)
#define VM_STEADY                                                                             \
    do { if constexpr (BN == 384) asm volatile("s_waitcnt vmcnt(8)" ::: "memory");            \
         else                     asm volatile("s_waitcnt vmcnt(6)" ::: "memory"); } while (0)

    STAGE_A(0); STAGE_B(0, 0); STAGE_B(0, 1);
    STAGE_A(1); STAGE_B(1, 0); STAGE_B(1, 1);
    VM_STEADY;
    BARX;
    LDA(0, afA); LDB(0, 0, bf0);
    asm volatile("s_waitcnt lgkmcnt(0)" ::: "memory");
    __builtin_amdgcn_sched_barrier(0);
    BARX;

#define TILE(T, AFc, AFn)                                                                     \
    {                                                                                         \
        LDB(T, 1, bf1);                                                                       \
        MFMAQ(0, AFc, bf0);                                                                   \
        BARX;                                                                                 \
        if ((T) + 2 < NT) { STAGE_A((T) + 2); STAGE_B((T) + 2, 0); STAGE_B((T) + 2, 1); }     \
        MFMAQ(1, AFc, bf1);                                                                   \
        if ((T) + 2 < NT)      { VM_STEADY; }                                                 \
        else if ((T) + 1 < NT) { asm volatile("s_waitcnt vmcnt(0)" ::: "memory"); }           \
        BARX;                                                                                 \
        if ((T) + 1 < NT) { LDA((T) + 1, AFn); LDB((T) + 1, 0, bf0); }                        \
    }

    for (int t = 0; t < NT; t += 2) {
        TILE(t,     afA, afB);
        TILE(t + 1, afB, afA);
    }
#undef TILE
#undef STAGE_A
#undef STAGE_B
#undef LDA
#undef LDB
#undef MFMAQ
#undef BARX
#undef VM_STEADY

#pragma unroll
    for (int nh = 0; nh < 2; ++nh)
#pragma unroll
    for (int i = 0; i < 4; ++i)
#pragma unroll
    for (int j = 0; j < NJH; ++j) {
        int n  = tn + wn * (BN / 4) + nh * (NJH * 16) + j * 16 + qlane;
        int m0 = tm + wm * 64 + i * 16 + qk * 4;
        if (MODE == 0) {
            int proj = n >> 10, dd = n & (DM - 1);
            const float* bb = (proj == 0) ? b0 : (proj == 1) ? b1 : b2;
            ushort* Cb      = (ushort*)((proj == 0) ? C0v : (proj == 1) ? C1v : C2v);
            float bv = bb[dd];
            int b = m0 >> 11, l = m0 & (LSEQ - 1);
            ushort4 val;
            val.x = f2b(acc[nh][i][j][0] + bv);
            val.y = f2b(acc[nh][i][j][1] + bv);
            val.z = f2b(acc[nh][i][j][2] + bv);
            val.w = f2b(acc[nh][i][j][3] + bv);
            *(ushort4*)(Cb + ((size_t)b * DM + dd) * LSEQ + l) = val;
        } else {
            float* C0 = (float*)C0v;
            float bv = b0[n];
#pragma unroll
            for (int r = 0; r < 4; ++r)
                C0[(size_t)(m0 + r) * N + n] = acc[nh][i][j][r] + bv;
        }
    }
}

// ---------------------------------------------------------------- FUSED double MFMA Toeplitz causal conv
// A-build: parity folded into the read address (b_el mod 4 loop-invariant), 5 dword reads + alignbit.
#define KSTR 2096
#define XSTR 2248

__global__ __launch_bounds__(256, 4) void conv_fused_kernel(const ushort* __restrict__ x,
                                                            const float* __restrict__ ker1,
                                                            const float* __restrict__ scale1,
                                                            const ushort* __restrict__ gate1,
                                                            const float* __restrict__ ker2,
                                                            const float* __restrict__ scale2,
                                                            const ushort* __restrict__ gate2,
                                                            ushort* __restrict__ out) {
    __shared__ ushort krev1[KSTR];
    __shared__ ushort krev2[KSTR];
    __shared__ ushort xs[4 * XSTR];
    const int d    = blockIdx.x;
    const int tid  = threadIdx.x;
    const int wave = tid >> 6;          // 0..3
    const int lane = tid & 63;

    {
        const ushort* src = x + ((size_t)wave * DM + d) * LSEQ + lane * 8;
        char* dst = (char*)xs + wave * (XSTR * 2) + 256;
#pragma unroll
        for (int c = 0; c < 4; ++c)
            __builtin_amdgcn_global_load_lds((const __attribute__((address_space(1))) void*)(src + c * 512),
                                             (__attribute__((address_space(3))) void*)(dst + c * 1024),
                                             16, 0, 0);
    }
    {
        int e0 = tid * 8;
        const float* k1p = ker1 + (size_t)d * LSEQ + e0;
        const float* k2p = ker2 + (size_t)d * LSEQ + e0;
        float4 a1 = *(const float4*)(k1p),     b1 = *(const float4*)(k1p + 4);
        float4 a2 = *(const float4*)(k2p),     b2 = *(const float4*)(k2p + 4);
        ushort4 o;                                    // krev[2060-e + j] = ker[e+3-j]
        o.x = f2b(a1.w); o.y = f2b(a1.z); o.z = f2b(a1.y); o.w = f2b(a1.x);
        *(ushort4*)(krev1 + (2060 - e0)) = o;
        o.x = f2b(b1.w); o.y = f2b(b1.z); o.z = f2b(b1.y); o.w = f2b(b1.x);
        *(ushort4*)(krev1 + (2056 - e0)) = o;
        o.x = f2b(a2.w); o.y = f2b(a2.z); o.z = f2b(a2.y); o.w = f2b(a2.x);
        *(ushort4*)(krev2 + (2060 - e0)) = o;
        o.x = f2b(b2.w); o.y = f2b(b2.z); o.z = f2b(b2.y); o.w = f2b(b2.x);
        *(ushort4*)(krev2 + (2056 - e0)) = o;
        uint4 z = {0, 0, 0, 0};
        if (tid < 2) {
            *(uint4*)((char*)krev1 + tid * 16) = z;
            *(uint4*)((char*)krev2 + tid * 16) = z;
        }
        if (tid >= 2 && tid < 6) {
            *(uint4*)((char*)krev1 + 4128 + (tid - 2) * 16) = z;
            *(uint4*)((char*)krev2 + 4128 + (tid - 2) * 16) = z;
        }
        if (tid >= 64 && tid < 128) {
            int b = (tid - 64) >> 4, c = (tid - 64) & 15;
            *(uint4*)((char*)xs + b * (XSTR * 2) + c * 16) = z;
        }
        if (tid >= 128 && tid < 144) {
            int b = (tid - 128) >> 2, c = (tid - 128) & 3;
            *(uint4*)((char*)xs + b * (XSTR * 2) + 4352 + c * 16) = z;
        }
    }
    __syncthreads();

    const int qn = lane & 15;
    const int qk = lane >> 4;

    int g[4] = {wave, 7 - wave, 8 + wave, 15 - wave};
    const int smax_all = 128 * (15 - wave) + 128;

    const int lbase = (qn & 3) * XSTR + 128 + 16 * (qn >> 2) + 8 * qk;

#define CSTEP(KR, ACC, SS, FP)                                                               \
    {                                                                                        \
        int b_el = 2063 - qn + 8 * qk - (SS);                                                \
        int A0 = b_el & ~1;                                                                  \
        uint sh = (uint)(b_el & 1) * 16u;                                                    \
        uint e0 = *(const uint*)((KR) + A0);                                                 \
        uint e1 = *(const uint*)((KR) + A0 + 2);                                             \
        uint e2 = *(const uint*)((KR) + A0 + 4);                                             \
        uint e3 = *(const uint*)((KR) + A0 + 6);                                             \
        uint e4 = *(const uint*)((KR) + A0 + 8);                                             \
        union { uint u[4]; short8 v; } Af;                                                   \
        Af.u[0] = __builtin_amdgcn_alignbit(e1, e0, sh);                                     \
        Af.u[1] = __builtin_amdgcn_alignbit(e2, e1, sh);                                     \
        Af.u[2] = __builtin_amdgcn_alignbit(e3, e2, sh);                                     \
        Af.u[3] = __builtin_amdgcn_alignbit(e4, e3, sh);                                     \
        _Pragma("unroll")                                                                    \
        for (int gi = 0; gi < 4; ++gi) {                                                     \
            if ((SS) <= 128 * g[gi] + 128) {                                                 \
                short8 fN = *(const short8*)(xs + lbase + 128 * g[gi] - (SS));               \
                ACC[gi][0] = __builtin_amdgcn_mfma_f32_16x16x32_bf16(Af.v, fN, ACC[gi][0], 0, 0, 0); \
                ACC[gi][1] = __builtin_amdgcn_mfma_f32_16x16x32_bf16(Af.v, FP[gi], ACC[gi][1], 0, 0, 0); \
                FP[gi] = fN;                                                                 \
            }                                                                                \
        }                                                                                    \
    }

    // ================= pass 1: k -> kv (in LDS) =================
    {
        floatx4 acc[4][2] = {};
        short8 fE[4], fO[4];
#pragma unroll
        for (int gi = 0; gi < 4; ++gi) {
            fE[gi] = *(const short8*)(xs + lbase + 128 * g[gi] + 64);
            fO[gi] = *(const short8*)(xs + lbase + 128 * g[gi] + 32);
        }
        for (int s = 0; s <= smax_all; s += 64) {
            CSTEP(krev1, acc, s, fE);
            if (s + 32 <= smax_all) CSTEP(krev1, acc, s + 32, fO);
        }

        __syncthreads();                       // all pass-1 LDS reads done before overwrite
        const float sc = scale1[d];
#pragma unroll
        for (int gi = 0; gi < 4; ++gi) {
#pragma unroll
            for (int m = 0; m < 2; ++m) {
                int p  = 8 * g[gi] + 4 * m + (qn >> 2);
                int b  = qn & 3;
                int l0 = 16 * p + 4 * qk;
                size_t off = ((size_t)b * DM + d) * LSEQ + l0;
                ushort4 xv = *(const ushort4*)(xs + b * XSTR + 128 + l0);   // own slots only
                ushort4 gv = *(const ushort4*)(gate1 + off);
                ushort4 ov;
                ov.x = f2b((acc[gi][m][0] + sc * b2f(xv.x)) * b2f(gv.x));
                ov.y = f2b((acc[gi][m][1] + sc * b2f(xv.y)) * b2f(gv.y));
                ov.z = f2b((acc[gi][m][2] + sc * b2f(xv.z)) * b2f(gv.z));
                ov.w = f2b((acc[gi][m][3] + sc * b2f(xv.w)) * b2f(gv.w));
                *(ushort4*)(xs + b * XSTR + 128 + l0) = ov;                 // kv into LDS
            }
        }
        __syncthreads();                       // kv complete before pass-2 reads
    }

    // ================= pass 2: kv -> yq (to global) =================
    {
        floatx4 acc[4][2] = {};
        short8 fE[4], fO[4];
#pragma unroll
        for (int gi = 0; gi < 4; ++gi) {
            fE[gi] = *(const short8*)(xs + lbase + 128 * g[gi] + 64);
            fO[gi] = *(const short8*)(xs + lbase + 128 * g[gi] + 32);
        }
        for (int s = 0; s <= smax_all; s += 64) {
            CSTEP(krev2, acc, s, fE);
            if (s + 32 <= smax_all) CSTEP(krev2, acc, s + 32, fO);
        }

        const float sc = scale2[d];
#pragma unroll
        for (int gi = 0; gi < 4; ++gi) {
#pragma unroll
            for (int m = 0; m < 2; ++m) {
                int p  = 8 * g[gi] + 4 * m + (qn >> 2);
                int b  = qn & 3;
                int l0 = 16 * p + 4 * qk;
                size_t off = ((size_t)b * DM + d) * LSEQ + l0;
                ushort4 xv = *(const ushort4*)(xs + b * XSTR + 128 + l0);
                ushort4 gv = *(const ushort4*)(gate2 + off);
                ushort4 ov;
                ov.x = f2b((acc[gi][m][0] + sc * b2f(xv.x)) * b2f(gv.x));
                ov.y = f2b((acc[gi][m][1] + sc * b2f(xv.y)) * b2f(gv.y));
                ov.z = f2b((acc[gi][m][2] + sc * b2f(xv.z)) * b2f(gv.z));
                ov.w = f2b((acc[gi][m][3] + sc * b2f(xv.w)) * b2f(gv.w));
                *(ushort4*)(out + off) = ov;
            }
        }
    }
#undef CSTEP
}

// ---------------------------------------------------------------- (B,DM,L) bf16 -> (B*L,DM) bf16
__global__ __launch_bounds__(256) void transpose_bf16(const ushort* __restrict__ in,
                                                      ushort* __restrict__ out) {
    __shared__ ushort t[32][36];
    const int l0 = blockIdx.x * 32;
    const int d0 = blockIdx.y * 32;
    const int b  = blockIdx.z;
    const int q  = threadIdx.x & 7;
    const int r  = threadIdx.x >> 3;
    *(ushort4*)(&t[r][q * 4]) = *(const ushort4*)(in + ((size_t)b * DM + d0 + r) * LSEQ + l0 + q * 4);
    __syncthreads();
    ushort4 o;
    o.x = t[q * 4 + 0][r]; o.y = t[q * 4 + 1][r]; o.z = t[q * 4 + 2][r]; o.w = t[q * 4 + 3][r];
    *(ushort4*)(out + ((size_t)b * LSEQ + l0 + r) * DM + d0 + q * 4) = o;
}

// ---------------------------------------------------------------- launch
extern "C" void kernel_launch(void* const* d_in, const int* in_sizes, int n_in,
                              void* d_out, int out_size, void* d_ws, size_t ws_size,
                              hipStream_t stream) {
    const float* u        = (const float*)d_in[0];
    const float* Wq       = (const float*)d_in[1];
    const float* bq       = (const float*)d_in[2];
    const float* Wk       = (const float*)d_in[3];
    const float* bk       = (const float*)d_in[4];
    const float* Wv       = (const float*)d_in[5];
    const float* bv       = (const float*)d_in[6];
    const float* k_kernel = (const float*)d_in[7];
    const float* k_D      = (const float*)d_in[8];
    const float* ssm_ker  = (const float*)d_in[9];
    const float* Dv       = (const float*)d_in[10];
    const float* Wo       = (const float*)d_in[11];
    const float* bo       = (const float*)d_in[12];
    float* outp = (float*)d_out;

    char* ws = (char*)d_ws;
    ushort* Q    = (ushort*)(ws);                    // 16 MB (bf16 b,d,l)
    ushort* KV   = (ushort*)(ws + (16ull << 20));    // 16 MB (k -> yq, in place)
    ushort* V    = (ushort*)(ws + (32ull << 20));    // 16 MB
    ushort* U16  = (ushort*)(ws + (48ull << 20));    // 16 MB (u bf16)
    ushort* YT   = (ushort*)(ws + (64ull << 20));    // 16 MB (yq transposed)
    ushort* Wcat = (ushort*)(ws + (80ull << 20));    // 8 MB  (Wq|Wk|Wv|Wo bf16)

    const int nu = NB * LSEQ * DM / 8, nw = 4 * DM * DM / 8;
    cvt_all_kernel<<<(nu + nw) / 256, 256, 0, stream>>>(u, Wq, Wk, Wv, Wo, U16, Wcat);

    // fused q/k/v projection: M=8192, N=3072, K=1024; 128x384 tiles -> 512 blocks = 2 exact rounds
    dim3 g1(3 * DM / 384, NB * LSEQ / 128);
    gemm_v2<0, 384><<<g1, 512, 0, stream>>>(U16, Wcat, bq, bk, bv, Q, KV, V,
                                            3 * DM, 3 * DM / 384);

    // fused double conv: kv = (k_kernel (*) k + k_D*k) * v ; yq = (ssm_kernel (*) kv + D*kv) * q
    conv_fused_kernel<<<DM, 256, 0, stream>>>(KV, k_kernel, k_D, V, ssm_ker, Dv, Q, KV);

    // (B,DM,L) bf16 -> (B*L,DM) bf16
    dim3 g2(LSEQ / 32, DM / 32, NB);
    transpose_bf16<<<g2, 256, 0, stream>>>(KV, YT);

    // out = YT @ Wo^T + bo : M=8192, N=1024, K=1024; 128x256 tiles -> 256 blocks = 1 exact round
    dim3 g3(DM / 256, NB * LSEQ / 128);
    gemm_v2<1, 256><<<g3, 512, 0, stream>>>(YT, Wcat + 3 * DM * DM, bo, bo, bo,
                                            outp, outp, outp, DM, DM / 256);
}